// Round 1
// 163.113 us; speedup vs baseline: 1.0470x; 1.0470x over previous
//
#include <hip/hip_runtime.h>

// SSIM loss via separable 11-tap Gaussian. R11: both conv passes moved onto
// matrix cores (v_mfma_f32_16x16x32_f16). R10 was VALU-issue-bound
// (VALUBusy 53%, MfmaUtil 0, HBM 25%): ~60% of VALU issue was pk_fma/fdot2
// conv arithmetic. A separable conv is a banded-matrix multiply, so:
//  - Stage x,y as f16 COL-PAIR packed rows (74 rows x 44 cols; word = 2
//    adjacent cols; stride 22 words -> conflict-free b64 frag reads).
//  - Phase B (horizontal): D[band row][out col] = A_data(16x32 cols) x
//    B_taps(32x16 band). 5 bands x 2 col-tiles x 5 qty = 50 MFMA/block.
//    f32 accum -> pk f16 row-pairs into hq (37 rp x 34 w; 34%32=2 spreads
//    banks, phase-C reads are 2-way = free). Band 4 = rows 58..73 overlaps
//    band 3 (duplicate stores bit-identical -> benign), so staging stays at
//    74 rows and stores need no predicates.
//  - Phase C (vertical): D[out row][col] = A_taps(16x32 band) x B_h(32x16).
//    Wave w owns out rows 16w..15; wave 3 uses a -6-shifted band (reads h
//    rows 42..73) so hq never needs rows > 73. 40 MFMA/block.
// Epilogue: C/D layout col=lane&15, row=4*(lane>>4)+reg -> 8 px/lane SSIM,
// same wave reduce + per-block store + reduce kernel as R10.
// Invariants kept: LDS <= 40KB (38.3KB, 4 blocks/CU), 256 threads active in
// every phase, 3 barriers.

typedef __fp16 f16x8 __attribute__((ext_vector_type(8)));
typedef float f32x4 __attribute__((ext_vector_type(4)));
typedef unsigned u32x2 __attribute__((ext_vector_type(2)));
typedef unsigned u32x4 __attribute__((ext_vector_type(4)));

__device__ __forceinline__ unsigned pk2(float a, float b) {
    return __builtin_bit_cast(unsigned, __builtin_amdgcn_cvt_pkrtz(a, b));
}
__device__ __forceinline__ f32x4 mfma16(f16x8 a, f16x8 b, f32x4 c) {
    return __builtin_amdgcn_mfma_f32_16x16x32_f16(a, b, c, 0, 0, 0);
}
__device__ __forceinline__ f16x8 ld8(const unsigned* p) {
    const u32x2 a = *(const u32x2*)p;        // 8B-aligned (even word index)
    const u32x2 b = *(const u32x2*)(p + 2);
    const u32x4 w = {a.x, a.y, b.x, b.y};
    return __builtin_bit_cast(f16x8, w);
}

#define SXW 22   // staged words/row (44 f16 cols); 22*m mod 32 hits all even banks
#define HPW 34   // hq words/row-pair (32 cols + 2 pad)

__global__ __launch_bounds__(256, 4) void ssim_main(
    const float* __restrict__ xg, const float* __restrict__ yg,
    const float* __restrict__ w2d, float* __restrict__ part)
{
    __shared__ __align__(16) unsigned sx[74 * SXW];      // 6.4 KB
    __shared__ __align__(16) unsigned sy[74 * SXW];      // 6.4 KB
    __shared__ __align__(16) unsigned hq[5][37 * HPW];   // 24.6 KB
    __shared__ float gsf[12];
    __shared__ float wred[4];

    const int tid = threadIdx.x;

    // 1D kernel = row sums of the 2D window (window = outer(g,g), sum 1).
    // gsf[11] = 0 sentinel for the clamped tap lookup below.
    if (tid < 12) {
        float s = 0.0f;
        if (tid < 11) {
            #pragma unroll
            for (int j = 0; j < 11; ++j) s += w2d[tid * 11 + j];
        }
        gsf[tid] = s;
    }

    const int x0 = blockIdx.x * 32 - 6;   // even => float2 loads stay 8B-aligned
    const int y0 = blockIdx.y * 64 - 5;
    const size_t zoff = (size_t)blockIdx.z * (512 * 512);
    const float* __restrict__ xp = xg + zoff;
    const float* __restrict__ yp = yg + zoff;

    // Phase A: stage 74 rows x 22 col-pair words, zero-padded at edges.
    const bool interior = (x0 >= 0) & (x0 + 43 < 512) & (y0 >= 0) & (y0 + 73 < 512);
    if (interior) {
        for (int it = tid; it < 74 * SXW; it += 256) {
            const int r = it / SXW, cw = it - r * SXW;
            const int o = (y0 + r) * 512 + x0 + 2 * cw;
            const float2 vx = *(const float2*)&xp[o];
            const float2 vy = *(const float2*)&yp[o];
            sx[it] = pk2(vx.x, vx.y);
            sy[it] = pk2(vy.x, vy.y);
        }
    } else {
        for (int it = tid; it < 74 * SXW; it += 256) {
            const int r = it / SXW, cw = it - r * SXW;
            const int gr = y0 + r, gc = x0 + 2 * cw;
            float xv0 = 0.f, xv1 = 0.f, yv0 = 0.f, yv1 = 0.f;
            if ((unsigned)gr < 512u) {
                const int o = gr * 512 + gc;
                if ((unsigned)gc < 512u)       { xv0 = xp[o];     yv0 = yp[o]; }
                if ((unsigned)(gc + 1) < 512u) { xv1 = xp[o + 1]; yv1 = yp[o + 1]; }
            }
            sx[it] = pk2(xv0, xv1);
            sy[it] = pk2(yv0, yv1);
        }
    }
    __syncthreads();

    const int lane = tid & 63, wv = tid >> 6;
    const int lm = lane & 15, lg = lane >> 4;

    // f16 taps with center correction (f16 tap sum ~= 1). Every thread
    // derives the identical correction; tap lookup is a clamped dynamic LDS
    // index (register arrays + runtime index would spill to scratch).
    float ssum = 0.0f;
    #pragma unroll
    for (int k = 0; k < 11; ++k)
        if (k != 5) ssum += (float)(__fp16)gsf[k];
    const __fp16 cc = (__fp16)(1.0f - ssum);
    auto tap = [&](int t) -> __fp16 {
        const unsigned u = ((unsigned)t <= 11u) ? (unsigned)t : 11u;  // ->0
        const __fp16 hv = (__fp16)gsf[u];
        return (t == 5) ? cc : hv;
    };

    // Tap fragments (per lane, k = 8*lg + e):
    //  Phase B, B operand (taps, col n = lm):
    //    tile0: staged col k   -> tap t = k - n - 1   (k in [n+1,  n+11])
    //    tile1: staged col 12+k-> tap t = k - n - 5   (k in [n+5,  n+15])
    //  Phase C, A operand (taps, out row m = lm):
    //    waves 0-2 read hq rows 16w+k: t = k - m       (k in [m,    m+10])
    //    wave 3  reads hq rows 42+k:   t = k - m - 6   (k in [m+6,  m+16])
    f16x8 bt0, bt1, afr;
    const int dd = (wv == 3) ? -6 : 0;
    #pragma unroll
    for (int e = 0; e < 8; ++e) {
        const int k = 8 * lg + e;
        bt0[e] = tap(k - lm - 1);
        bt1[e] = tap(k - lm - 5);
        afr[e] = tap(k - lm + dd);
    }

    // Phase B: horizontal conv as MFMA. 10 wave-items = (band b, col-tile tl).
    // Band rows: 0,16,32,48,58 (band 4 overlaps band 3 -> no predicates).
    for (int i = wv; i < 10; i += 4) {
        const int b = i >> 1, tl = i & 1;
        const int rb = (b == 4) ? 58 : 16 * b;
        const int sbase = (rb + lm) * SXW + 6 * tl + 4 * lg;
        const f16x8 xa = ld8(&sx[sbase]);
        const f16x8 ya = ld8(&sy[sbase]);
        const f16x8 bt = tl ? bt1 : bt0;
        const f32x4 z4 = {0.f, 0.f, 0.f, 0.f};
        const f32x4 dmx = mfma16(xa, bt, z4);
        const f32x4 dmy = mfma16(ya, bt, z4);
        const f32x4 dxx = mfma16(xa * xa, bt, z4);
        const f32x4 dyy = mfma16(ya * ya, bt, z4);
        const f32x4 dxy = mfma16(xa * ya, bt, z4);
        // D: col = lm (+16*tl), rows rb + 4*lg + {0..3} -> two row-pair words.
        const int rp0 = (rb >> 1) + 2 * lg;          // <= 35; rp0+1 <= 36
        const int col = lm + 16 * tl;
        hq[0][rp0 * HPW + col]       = pk2(dmx[0], dmx[1]);
        hq[0][(rp0 + 1) * HPW + col] = pk2(dmx[2], dmx[3]);
        hq[1][rp0 * HPW + col]       = pk2(dmy[0], dmy[1]);
        hq[1][(rp0 + 1) * HPW + col] = pk2(dmy[2], dmy[3]);
        hq[2][rp0 * HPW + col]       = pk2(dxx[0], dxx[1]);
        hq[2][(rp0 + 1) * HPW + col] = pk2(dxx[2], dxx[3]);
        hq[3][rp0 * HPW + col]       = pk2(dyy[0], dyy[1]);
        hq[3][(rp0 + 1) * HPW + col] = pk2(dyy[2], dyy[3]);
        hq[4][rp0 * HPW + col]       = pk2(dxy[0], dxy[1]);
        hq[4][(rp0 + 1) * HPW + col] = pk2(dxy[2], dxy[3]);
    }
    __syncthreads();

    // Phase C: vertical conv as MFMA. Wave w -> out rows 16w..16w+15.
    f32x4 acc[2][5];
    #pragma unroll
    for (int ch = 0; ch < 2; ++ch)
        #pragma unroll
        for (int q = 0; q < 5; ++q)
            acc[ch][q] = (f32x4){0.f, 0.f, 0.f, 0.f};

    const int rpb = (wv == 3) ? 21 : 8 * wv;   // hq row-pair base of K window
    #pragma unroll
    for (int ch = 0; ch < 2; ++ch) {
        const int cb = (rpb + 4 * lg) * HPW + lm + 16 * ch;
        #pragma unroll
        for (int q = 0; q < 5; ++q) {
            const unsigned* hp = hq[q];
            const u32x4 w4 = {hp[cb], hp[cb + HPW],
                              hp[cb + 2 * HPW], hp[cb + 3 * HPW]};
            acc[ch][q] = mfma16(afr, __builtin_bit_cast(f16x8, w4), acc[ch][q]);
        }
    }

    // SSIM epilogue: lane holds out col 16ch+lm, rows 16wv+4lg+{0..3}.
    float lsum = 0.0f;
    const float C1 = 1e-4f, C2 = 9e-4f;
    #pragma unroll
    for (int ch = 0; ch < 2; ++ch) {
        #pragma unroll
        for (int r = 0; r < 4; ++r) {
            const float mx = acc[ch][0][r], my = acc[ch][1][r];
            const float exx = acc[ch][2][r], eyy = acc[ch][3][r];
            const float exy = acc[ch][4][r];
            const float mx2 = mx * mx, my2 = my * my, mxy = mx * my;
            const float vx = exx - mx2, vy = eyy - my2, vxy = exy - mxy;
            const float num = (2.0f * mxy + C1) * (2.0f * vxy + C2);
            const float den = (mx2 + my2 + C1) * (vx + vy + C2) + 1e-12f;
            lsum = fmaf(num, __builtin_amdgcn_rcpf(den), lsum);
        }
    }

    // Wave reduce -> cross-wave via LDS -> one plain store per block.
    #pragma unroll
    for (int off = 32; off > 0; off >>= 1)
        lsum += __shfl_down(lsum, off, 64);
    if ((tid & 63) == 0) wred[tid >> 6] = lsum;
    __syncthreads();
    if (tid == 0) {
        const int bid = (blockIdx.z * gridDim.y + blockIdx.y) * gridDim.x
                        + blockIdx.x;
        part[bid] = wred[0] + wred[1] + wred[2] + wred[3];
    }
}

__global__ __launch_bounds__(256) void ssim_reduce(
    const float* __restrict__ part, float* __restrict__ out,
    int n, float invN)
{
    __shared__ float wred[4];
    float s = 0.0f;
    for (int i = threadIdx.x; i < n; i += 256) s += part[i];
    #pragma unroll
    for (int off = 32; off > 0; off >>= 1)
        s += __shfl_down(s, off, 64);
    if ((threadIdx.x & 63) == 0) wred[threadIdx.x >> 6] = s;
    __syncthreads();
    if (threadIdx.x == 0)
        out[0] = 1.0f - (wred[0] + wred[1] + wred[2] + wred[3]) * invN;
}

extern "C" void kernel_launch(void* const* d_in, const int* in_sizes, int n_in,
                              void* d_out, int out_size, void* d_ws, size_t ws_size,
                              hipStream_t stream) {
    const float* x   = (const float*)d_in[0];
    const float* y   = (const float*)d_in[1];
    const float* w2d = (const float*)d_in[2];  // (3,1,11,11); channels identical
    float* out  = (float*)d_out;
    float* part = (float*)d_ws;                // 6144 floats = 24 KB

    const int H = 512, W = 512;
    const int total = in_sizes[0];              // 16*3*512*512
    const int Z = total / (H * W);              // 48

    dim3 grid(W / 32, H / 64, Z);               // 16 x 8 x 48 = 6144 blocks
    const int nblocks = (W / 32) * (H / 64) * Z;
    ssim_main<<<grid, 256, 0, stream>>>(x, y, w2d, part);

    const float invN = 1.0f / (float)total;
    ssim_reduce<<<1, 256, 0, stream>>>(part, out, nblocks, invN);
}

// Round 2
// 150.395 us; speedup vs baseline: 1.1355x; 1.0846x over previous
//
#include <hip/hip_runtime.h>

// SSIM loss via separable 11-tap Gaussian, both conv passes on matrix cores
// (v_mfma_f32_16x16x32_f16). R12 = R11 + occupancy/overlap fix. R11 was
// latency-bound: VALU 33%, HBM 26%, Mfma 4.5%, occupancy 38% (38.4KB LDS ->
// 4 blocks/CU); phase A (pure HBM) and phases B/C (pure LDS/MFMA) are
// barrier-serialized, and 4 phase-locked blocks/CU can't overlap them.
//  - hq quantity-chunking: B/C run 3x over a 2-slot hq ({mx,my},{xx,yy},
//    {xy}); same MFMA count, 4 extra barriers, LDS 38.2 -> 22.9 KB
//    (23040B @ 512B granule) => 7 blocks/CU, 28/32 waves.
//  - HPW 34->33 to fit under 160/7 KB (C-reads 4-way on 1/4 of banks, ~free).
//  - XCD-aware bijective block swizzle (nwg%8==0): neighbor tiles share halo
//    cachelines in the same XCD L2 -> FETCH_SIZE toward the 101MB ideal.
// Layouts unchanged from R11:
//  - sx/sy: f16 col-pair packed rows, 74 x 22 words (44 cols), b64-aligned.
//  - Phase B: D[band row][out col] = A_data(16x32) x B_taps(32x16); 5 bands
//    (0,16,32,48,58; band4 overlaps band3 -> duplicate identical stores,
//    benign) x 2 col-tiles; f32 accum -> pk f16 row-pairs into hq.
//  - Phase C: D[out row][col] = A_taps(16x32) x B_h(32x16); wave w -> rows
//    16w..16w+15, wave 3 uses -6-shifted band so hq rows stay <= 73.
// Epilogue: C/D col=lane&15, row=4*(lane>>4)+reg -> 8 px/lane SSIM; wave
// reduce -> per-block plain store -> reduce kernel.

typedef __fp16 f16x8 __attribute__((ext_vector_type(8)));
typedef float f32x4 __attribute__((ext_vector_type(4)));
typedef unsigned u32x2 __attribute__((ext_vector_type(2)));
typedef unsigned u32x4 __attribute__((ext_vector_type(4)));

__device__ __forceinline__ unsigned pk2(float a, float b) {
    return __builtin_bit_cast(unsigned, __builtin_amdgcn_cvt_pkrtz(a, b));
}
__device__ __forceinline__ f32x4 mfma16(f16x8 a, f16x8 b, f32x4 c) {
    return __builtin_amdgcn_mfma_f32_16x16x32_f16(a, b, c, 0, 0, 0);
}
__device__ __forceinline__ f16x8 ld8(const unsigned* p) {
    const u32x2 a = *(const u32x2*)p;        // 8B-aligned (even word index)
    const u32x2 b = *(const u32x2*)(p + 2);
    const u32x4 w = {a.x, a.y, b.x, b.y};
    return __builtin_bit_cast(f16x8, w);
}

#define SXW 22   // staged words/row (44 f16 cols)
#define HPW 33   // hq words/row-pair (32 cols + 1 pad); 2 slots only

__global__ __launch_bounds__(256, 7) void ssim_main(
    const float* __restrict__ xg, const float* __restrict__ yg,
    const float* __restrict__ w2d, float* __restrict__ part)
{
    __shared__ __align__(16) unsigned sx[74 * SXW];      // 6512 B
    __shared__ __align__(16) unsigned sy[74 * SXW];      // 6512 B
    __shared__ __align__(16) unsigned hq[2][37 * HPW];   // 9768 B
    __shared__ float gsf[12];
    __shared__ float wred[4];
    // total 22856 B -> 23040 alloc -> 7 blocks/CU

    const int tid = threadIdx.x;

    // 1D kernel = row sums of the 2D window (window = outer(g,g), sum 1).
    // gsf[11] = 0 sentinel for the clamped tap lookup below.
    if (tid < 12) {
        float s = 0.0f;
        if (tid < 11) {
            #pragma unroll
            for (int j = 0; j < 11; ++j) s += w2d[tid * 11 + j];
        }
        gsf[tid] = s;
    }

    // XCD-aware bijective swizzle: nwg = 128*Z, always %8==0. Consecutive
    // hardware blocks on one XCD get consecutive logical tiles.
    const int nwg = 128 * (int)gridDim.z;
    const int flat = (int)blockIdx.x + 16 * ((int)blockIdx.y + 8 * (int)blockIdx.z);
    const int swz = (flat & 7) * (nwg >> 3) + (flat >> 3);
    const int bx = swz & 15, by = (swz >> 4) & 7, bz = swz >> 7;

    const int x0 = bx * 32 - 6;   // even => float2 loads stay 8B-aligned
    const int y0 = by * 64 - 5;
    const size_t zoff = (size_t)bz * (512 * 512);
    const float* __restrict__ xp = xg + zoff;
    const float* __restrict__ yp = yg + zoff;

    // Phase A: stage 74 rows x 22 col-pair words, zero-padded at edges.
    const bool interior = (x0 >= 0) & (x0 + 43 < 512) & (y0 >= 0) & (y0 + 73 < 512);
    if (interior) {
        for (int it = tid; it < 74 * SXW; it += 256) {
            const int r = it / SXW, cw = it - r * SXW;
            const int o = (y0 + r) * 512 + x0 + 2 * cw;
            const float2 vx = *(const float2*)&xp[o];
            const float2 vy = *(const float2*)&yp[o];
            sx[it] = pk2(vx.x, vx.y);
            sy[it] = pk2(vy.x, vy.y);
        }
    } else {
        for (int it = tid; it < 74 * SXW; it += 256) {
            const int r = it / SXW, cw = it - r * SXW;
            const int gr = y0 + r, gc = x0 + 2 * cw;
            float xv0 = 0.f, xv1 = 0.f, yv0 = 0.f, yv1 = 0.f;
            if ((unsigned)gr < 512u) {
                const int o = gr * 512 + gc;
                if ((unsigned)gc < 512u)       { xv0 = xp[o];     yv0 = yp[o]; }
                if ((unsigned)(gc + 1) < 512u) { xv1 = xp[o + 1]; yv1 = yp[o + 1]; }
            }
            sx[it] = pk2(xv0, xv1);
            sy[it] = pk2(yv0, yv1);
        }
    }
    __syncthreads();

    const int lane = tid & 63, wv = tid >> 6;
    const int lm = lane & 15, lg = lane >> 4;

    // f16 taps with center correction (f16 tap sum ~= 1). Clamped dynamic
    // LDS index (register array + runtime index would spill to scratch).
    float ssum = 0.0f;
    #pragma unroll
    for (int k = 0; k < 11; ++k)
        if (k != 5) ssum += (float)(__fp16)gsf[k];
    const __fp16 cc = (__fp16)(1.0f - ssum);
    auto tap = [&](int t) -> __fp16 {
        const unsigned u = ((unsigned)t <= 11u) ? (unsigned)t : 11u;  // ->0
        const __fp16 hv = (__fp16)gsf[u];
        return (t == 5) ? cc : hv;
    };

    // Tap fragments (per lane, k = 8*lg + e):
    //  Phase B (B operand, out col n = lm):
    //    tile0: staged col k    -> tap t = k - n - 1
    //    tile1: staged col 12+k -> tap t = k - n - 5
    //  Phase C (A operand, out row m = lm):
    //    waves 0-2 read hq rows 16w+k: t = k - m
    //    wave 3  reads hq rows 42+k:   t = k - m - 6
    f16x8 bt0, bt1, afr;
    const int dd = (wv == 3) ? -6 : 0;
    #pragma unroll
    for (int e = 0; e < 8; ++e) {
        const int k = 8 * lg + e;
        bt0[e] = tap(k - lm - 1);
        bt1[e] = tap(k - lm - 5);
        afr[e] = tap(k - lm + dd);
    }

    f32x4 acc[2][5];
    #pragma unroll
    for (int ch = 0; ch < 2; ++ch)
        #pragma unroll
        for (int q = 0; q < 5; ++q)
            acc[ch][q] = (f32x4){0.f, 0.f, 0.f, 0.f};

    const int rpb = (wv == 3) ? 21 : 8 * wv;   // hq row-pair base of C window

    // Chunks over quantities: {x,y} -> {x*x,y*y} -> {x*y}, reusing hq[0..1].
    #pragma unroll
    for (int chunk = 0; chunk < 3; ++chunk) {
        // Phase B: horizontal conv as MFMA. 10 items = (band b, col-tile tl);
        // band rows 0,16,32,48,58.
        for (int i = wv; i < 10; i += 4) {
            const int b = i >> 1, tl = i & 1;
            const int rb = (b == 4) ? 58 : 16 * b;
            const int sbase = (rb + lm) * SXW + 6 * tl + 4 * lg;
            const f16x8 xa = ld8(&sx[sbase]);
            const f16x8 ya = ld8(&sy[sbase]);
            const f16x8 bt = tl ? bt1 : bt0;
            const f32x4 z4 = {0.f, 0.f, 0.f, 0.f};
            f32x4 d0, d1;
            if (chunk == 0)      { d0 = mfma16(xa, bt, z4);      d1 = mfma16(ya, bt, z4); }
            else if (chunk == 1) { d0 = mfma16(xa * xa, bt, z4); d1 = mfma16(ya * ya, bt, z4); }
            else                 { d0 = mfma16(xa * ya, bt, z4); }
            // D: col = lm (+16*tl), rows rb + 4*lg + {0..3} -> two rp words.
            const int rp0 = (rb >> 1) + 2 * lg;
            const int col = lm + 16 * tl;
            hq[0][rp0 * HPW + col]       = pk2(d0[0], d0[1]);
            hq[0][(rp0 + 1) * HPW + col] = pk2(d0[2], d0[3]);
            if (chunk < 2) {
                hq[1][rp0 * HPW + col]       = pk2(d1[0], d1[1]);
                hq[1][(rp0 + 1) * HPW + col] = pk2(d1[2], d1[3]);
            }
        }
        __syncthreads();

        // Phase C: vertical conv as MFMA into the chunk's accumulators.
        #pragma unroll
        for (int ch = 0; ch < 2; ++ch) {
            const int cb = (rpb + 4 * lg) * HPW + lm + 16 * ch;
            #pragma unroll
            for (int s = 0; s < 2; ++s) {
                if (chunk == 2 && s == 1) continue;
                const unsigned* hp = hq[s];
                const u32x4 w4 = {hp[cb], hp[cb + HPW],
                                  hp[cb + 2 * HPW], hp[cb + 3 * HPW]};
                acc[ch][2 * chunk + s] =
                    mfma16(afr, __builtin_bit_cast(f16x8, w4), acc[ch][2 * chunk + s]);
            }
        }
        if (chunk < 2) __syncthreads();   // hq reads done before next B rewrites
    }

    // SSIM epilogue: lane holds out col 16ch+lm, rows 16wv+4lg+{0..3}.
    float lsum = 0.0f;
    const float C1 = 1e-4f, C2 = 9e-4f;
    #pragma unroll
    for (int ch = 0; ch < 2; ++ch) {
        #pragma unroll
        for (int r = 0; r < 4; ++r) {
            const float mx = acc[ch][0][r], my = acc[ch][1][r];
            const float exx = acc[ch][2][r], eyy = acc[ch][3][r];
            const float exy = acc[ch][4][r];
            const float mx2 = mx * mx, my2 = my * my, mxy = mx * my;
            const float vx = exx - mx2, vy = eyy - my2, vxy = exy - mxy;
            const float num = (2.0f * mxy + C1) * (2.0f * vxy + C2);
            const float den = (mx2 + my2 + C1) * (vx + vy + C2) + 1e-12f;
            lsum = fmaf(num, __builtin_amdgcn_rcpf(den), lsum);
        }
    }

    // Wave reduce -> cross-wave via LDS -> one plain store per block.
    #pragma unroll
    for (int off = 32; off > 0; off >>= 1)
        lsum += __shfl_down(lsum, off, 64);
    if ((tid & 63) == 0) wred[tid >> 6] = lsum;
    __syncthreads();
    if (tid == 0) part[swz] = wred[0] + wred[1] + wred[2] + wred[3];
}

__global__ __launch_bounds__(256) void ssim_reduce(
    const float* __restrict__ part, float* __restrict__ out,
    int n, float invN)
{
    __shared__ float wred[4];
    float s = 0.0f;
    for (int i = threadIdx.x; i < n; i += 256) s += part[i];
    #pragma unroll
    for (int off = 32; off > 0; off >>= 1)
        s += __shfl_down(s, off, 64);
    if ((threadIdx.x & 63) == 0) wred[threadIdx.x >> 6] = s;
    __syncthreads();
    if (threadIdx.x == 0)
        out[0] = 1.0f - (wred[0] + wred[1] + wred[2] + wred[3]) * invN;
}

extern "C" void kernel_launch(void* const* d_in, const int* in_sizes, int n_in,
                              void* d_out, int out_size, void* d_ws, size_t ws_size,
                              hipStream_t stream) {
    const float* x   = (const float*)d_in[0];
    const float* y   = (const float*)d_in[1];
    const float* w2d = (const float*)d_in[2];  // (3,1,11,11); channels identical
    float* out  = (float*)d_out;
    float* part = (float*)d_ws;                // 6144 floats = 24 KB

    const int H = 512, W = 512;
    const int total = in_sizes[0];              // 16*3*512*512
    const int Z = total / (H * W);              // 48

    dim3 grid(W / 32, H / 64, Z);               // 16 x 8 x 48 = 6144 blocks
    const int nblocks = (W / 32) * (H / 64) * Z;
    ssim_main<<<grid, 256, 0, stream>>>(x, y, w2d, part);

    const float invN = 1.0f / (float)total;
    ssim_reduce<<<1, 256, 0, stream>>>(part, out, nblocks, invN);
}